// Round 3
// baseline (192.674 us; speedup 1.0000x reference)
//
#include <hip/hip_runtime.h>
#include <hip/hip_bf16.h>

#define DIM   128
#define NH    8
#define INNER 512
#define HD    64
#define BSZ   4
#define NSEQ  1024
#define PEC   32
#define BH    32   // BSZ*NH

typedef __attribute__((ext_vector_type(4))) float f32x4;
typedef __attribute__((ext_vector_type(8))) short s16x8;
typedef __attribute__((ext_vector_type(4))) unsigned short u16x4;

__device__ __forceinline__ unsigned short f2bf(float f) {
    unsigned u = __float_as_uint(f);
    u += 0x7fffu + ((u >> 16) & 1u);
    return (unsigned short)(u >> 16);
}

__device__ __forceinline__ float bf2f(short s) {
    return __uint_as_float(((unsigned)(unsigned short)s) << 16);
}

__device__ __forceinline__ s16x8 load8bf(const float* p) {
    f32x4 a = *(const f32x4*)p;
    f32x4 b = *(const f32x4*)(p + 4);
    s16x8 r;
    r[0] = (short)f2bf(a[0]); r[1] = (short)f2bf(a[1]);
    r[2] = (short)f2bf(a[2]); r[3] = (short)f2bf(a[3]);
    r[4] = (short)f2bf(b[0]); r[5] = (short)f2bf(b[1]);
    r[6] = (short)f2bf(b[2]); r[7] = (short)f2bf(b[3]);
    return r;
}

__device__ __forceinline__ f32x4 mfma16(s16x8 a, s16x8 b, f32x4 c) {
    return __builtin_amdgcn_mfma_f32_16x16x32_bf16(a, b, c, 0, 0, 0);
}

// ---------------------------------------------------------------------------
// K1: q/k/v projections.  q_ws,k_ws: bf16 [bh][n][d]  (q pre-scaled by 1/8)
//     vT_ws: bf16 [bh][d][n]  (transposed, bias added)
// ---------------------------------------------------------------------------
__global__ __launch_bounds__(256) void k_qkv(
    const float* __restrict__ x,
    const float* __restrict__ Wq, const float* __restrict__ Wk,
    const float* __restrict__ Wv, const float* __restrict__ bv,
    unsigned short* __restrict__ qws, unsigned short* __restrict__ kws,
    unsigned short* __restrict__ vtws)
{
    int lane = threadIdx.x & 63, wave = threadIdx.x >> 6;
    int lr = lane & 15, lg = lane >> 4;
    int ct   = blockIdx.x * 4 + wave;   // 0..95 column tile over 1536 cols
    int col0 = ct * 16;
    int m0   = blockIdx.y * 16;

    s16x8 a[4];
    const float* xrow = x + (m0 + lr) * DIM;
    #pragma unroll
    for (int kt = 0; kt < 4; ++kt) a[kt] = load8bf(xrow + kt * 32 + lg * 8);

    const float* W; int cbase; int which = col0 >> 9;
    if (which == 0)      { W = Wq; cbase = col0; }
    else if (which == 1) { W = Wk; cbase = col0 - 512; }
    else                 { W = Wv; cbase = col0 - 1024; }

    const float* wrow = W + (cbase + lr) * DIM;
    s16x8 bfr[4];
    #pragma unroll
    for (int kt = 0; kt < 4; ++kt) bfr[kt] = load8bf(wrow + kt * 32 + lg * 8);
    f32x4 acc = {0.f, 0.f, 0.f, 0.f};
    #pragma unroll
    for (int kt = 0; kt < 4; ++kt) acc = mfma16(a[kt], bfr[kt], acc);

    int colW = cbase + lr;          // 0..511 inside this projection
    int h = colW >> 6, d = colW & 63;
    int mB = m0 + lg * 4;           // 4 consecutive rows, same batch
    int b  = mB >> 10;
    int bh = b * NH + h;
    if (which == 2) {
        float bias = bv[colW];
        u16x4 pk;
        #pragma unroll
        for (int v = 0; v < 4; ++v) pk[v] = f2bf(acc[v] + bias);
        int n0 = mB & 1023;
        *(u16x4*)(vtws + (bh * HD + d) * NSEQ + n0) = pk;
    } else {
        #pragma unroll
        for (int v = 0; v < 4; ++v) {
            int n = (mB + v) & 1023;
            float val = acc[v];
            if (which == 0) qws[(bh * NSEQ + n) * HD + d] = f2bf(val * 0.125f);
            else            kws[(bh * NSEQ + n) * HD + d] = f2bf(val);
        }
    }
}

// ---------------------------------------------------------------------------
// K2: per (bh, 16 query rows): S = qk^T -> softmax -> attn bf16 [i][bh][j]
//     -> outv = P @ V (via vT) f32 [bh][n][d]
// v3: full K-slice register prefetch (32 loads in flight); V fragments issued
// before softmax so HBM/L2 latency hides under the exp passes.
// grid (64, 32), block 256.
// ---------------------------------------------------------------------------
__global__ __launch_bounds__(256) void k_attn(
    const unsigned short* __restrict__ qws, const unsigned short* __restrict__ kws,
    const unsigned short* __restrict__ vtws,
    unsigned short* __restrict__ attnw, float* __restrict__ outv)
{
    __shared__ unsigned short sS[16 * 1024];   // 32 KB bf16 [16][1024] swizzled
    int lane = threadIdx.x & 63, wave = threadIdx.x >> 6;
    int lr = lane & 15, lg = lane >> 4;
    int bh = blockIdx.y;
    int i0 = blockIdx.x * 16;

    auto sp = [&](int r, int j) -> unsigned short* {
        unsigned byte = (unsigned)(r * 2048 + j * 2);
        byte ^= (unsigned)((r & 7) << 4);
        return (unsigned short*)((char*)sS + byte);
    };

    // ---- phase 1: scores; wave w covers j in [w*256, w*256+256) ----
    s16x8 qf0, qf1;
    {
        const unsigned short* qrow = qws + (bh * NSEQ + i0 + lr) * HD;
        qf0 = *(const s16x8*)(qrow + lg * 8);
        qf1 = *(const s16x8*)(qrow + 32 + lg * 8);
    }
    s16x8 kf[32];
    {
        const unsigned short* kbase = kws + (bh * NSEQ + wave * 256) * HD;
        #pragma unroll
        for (int jt = 0; jt < 16; ++jt) {
            const unsigned short* krow = kbase + (jt * 16 + lr) * HD + lg * 8;
            kf[2 * jt]     = *(const s16x8*)(krow);
            kf[2 * jt + 1] = *(const s16x8*)(krow + 32);
        }
    }
    #pragma unroll
    for (int jt = 0; jt < 16; ++jt) {
        int j0 = wave * 256 + jt * 16;
        f32x4 acc = {0.f, 0.f, 0.f, 0.f};
        acc = mfma16(qf0, kf[2 * jt], acc);
        acc = mfma16(qf1, kf[2 * jt + 1], acc);
        #pragma unroll
        for (int v = 0; v < 4; ++v) *sp(lg * 4 + v, j0 + lr) = f2bf(acc[v]);
    }
    __syncthreads();

    // ---- issue V prefetch: latency hides under softmax ----
    int d0 = wave * 16;
    s16x8 vf[32];
    {
        const unsigned short* vbase = vtws + (bh * HD + d0 + lr) * NSEQ + lg * 8;
        #pragma unroll
        for (int kt = 0; kt < 32; ++kt) vf[kt] = *(const s16x8*)(vbase + kt * 32);
    }

    // ---- phase 2: softmax, 16 threads/row. pass A: max ----
    int r = threadIdx.x >> 4, c = threadIdx.x & 15;
    float mx = -3.0e38f;
    #pragma unroll
    for (int it = 0; it < 8; ++it) {
        s16x8 sv = *(s16x8*)sp(r, it * 128 + c * 8);
        #pragma unroll
        for (int u = 0; u < 8; ++u) mx = fmaxf(mx, bf2f(sv[u]));
    }
    #pragma unroll
    for (int off = 8; off; off >>= 1) mx = fmaxf(mx, __shfl_xor(mx, off, 16));

    // pass B: e = exp(S - mx), store e (bf16), accumulate sum
    float sum = 0.f;
    #pragma unroll
    for (int it = 0; it < 8; ++it) {
        unsigned short* p = sp(r, it * 128 + c * 8);
        s16x8 sv = *(s16x8*)p;
        s16x8 ev;
        #pragma unroll
        for (int u = 0; u < 8; ++u) {
            float e = __expf(bf2f(sv[u]) - mx);
            sum += e;
            ev[u] = (short)f2bf(e);
        }
        *(s16x8*)p = ev;
    }
    #pragma unroll
    for (int off = 8; off; off >>= 1) sum += __shfl_xor(sum, off, 16);
    float inv = 1.0f / sum;

    // pass C: P = e * inv -> LDS + global attn
    unsigned short* arow = attnw + ((i0 + r) * BH + bh) * NSEQ;
    #pragma unroll
    for (int it = 0; it < 8; ++it) {
        unsigned short* p = sp(r, it * 128 + c * 8);
        s16x8 ev = *(s16x8*)p;
        s16x8 pv;
        #pragma unroll
        for (int u = 0; u < 8; ++u) pv[u] = (short)f2bf(bf2f(ev[u]) * inv);
        *(s16x8*)p = pv;
        *(s16x8*)(arow + it * 128 + c * 8) = pv;
    }
    __syncthreads();

    // ---- phase 3: outv = P @ V from registers ----
    f32x4 oacc = {0.f, 0.f, 0.f, 0.f};
    #pragma unroll
    for (int kt = 0; kt < 32; ++kt) {
        s16x8 af = *(const s16x8*)sp(lr, kt * 32 + lg * 8);
        oacc = mfma16(af, vf[kt], oacc);
    }
    float* orow = outv + (bh * NSEQ + i0) * HD;
    #pragma unroll
    for (int v = 0; v < 4; ++v)
        orow[(lg * 4 + v) * HD + d0 + lr] = oacc[v];
}

// ---------------------------------------------------------------------------
// K3: per query row i: pes[bh][i][c] = attn[i] (32bh x 1024j) @ pe[i] (1024j x 32c)
// v3: all 32 attn A-fragments preloaded to registers; pe staging split into
// issue-early (global->reg) / commit-late (reg->LDS after MFMAs), 1 barrier/iter.
// grid (1024), block 256: 4 waves = 2 bh-halves x 2 c-halves.
// ---------------------------------------------------------------------------
__global__ __launch_bounds__(256) void k_pe(
    const unsigned short* __restrict__ attnw, const float* __restrict__ pe,
    float* __restrict__ pes)
{
    __shared__ unsigned short pt[2][PEC][136];   // 17.4 KB
    int i = blockIdx.x;
    int tid = threadIdx.x;
    int lane = tid & 63, wave = tid >> 6;
    int lr = lane & 15, lg = lane >> 4;
    int bh0 = (wave >> 1) * 16;
    int c0  = (wave & 1) * 16;
    const float* pei = pe + (size_t)i * NSEQ * PEC;
    int jp = tid & 63;        // j-pair index (covers 2 consecutive j)
    int cg = tid >> 6;        // c-octet

    // preload ALL attn A-fragments (64 VGPRs, consumed across the loop)
    s16x8 af[32];
    {
        const unsigned short* arow = attnw + ((size_t)i * BH + bh0 + lr) * NSEQ + lg * 8;
        #pragma unroll
        for (int t = 0; t < 32; ++t) af[t] = *(const s16x8*)(arow + t * 32);
    }

    f32x4 r0, r1, r2, r3;     // pe stage registers
    auto issue = [&](int blk) {
        const float* s0 = pei + (size_t)(blk * 128 + jp * 2) * PEC + cg * 8;
        r0 = *(const f32x4*)(s0);
        r1 = *(const f32x4*)(s0 + 4);
        r2 = *(const f32x4*)(s0 + PEC);
        r3 = *(const f32x4*)(s0 + PEC + 4);
    };
    auto commit = [&](int buf) {
        #pragma unroll
        for (int cc = 0; cc < 4; ++cc) {
            unsigned lo = f2bf(r0[cc]), hi = f2bf(r2[cc]);
            *(unsigned*)&pt[buf][cg * 8 + cc][jp * 2] = lo | (hi << 16);
        }
        #pragma unroll
        for (int cc = 0; cc < 4; ++cc) {
            unsigned lo = f2bf(r1[cc]), hi = f2bf(r3[cc]);
            *(unsigned*)&pt[buf][cg * 8 + 4 + cc][jp * 2] = lo | (hi << 16);
        }
    };

    issue(0); commit(0);
    __syncthreads();

    f32x4 acc = {0.f, 0.f, 0.f, 0.f};
    #pragma unroll
    for (int blk = 0; blk < 8; ++blk) {
        int cur = blk & 1;
        if (blk < 7) issue(blk + 1);
        #pragma unroll
        for (int kt = 0; kt < 4; ++kt) {
            s16x8 bf = *(const s16x8*)&pt[cur][c0 + lr][kt * 32 + lg * 8];
            acc = mfma16(af[blk * 4 + kt], bf, acc);
        }
        if (blk < 7) commit(cur ^ 1);
        __syncthreads();
    }
    #pragma unroll
    for (int v = 0; v < 4; ++v)
        pes[((bh0 + lg * 4 + v) * NSEQ + i) * PEC + c0 + lr] = acc[v];
}

// ---------------------------------------------------------------------------
// K4: t[b][n][h*64+d] = outv + pes @ Wpe^T + bpe   (bf16 packed)
// ---------------------------------------------------------------------------
__global__ __launch_bounds__(256) void k_comb(
    const float* __restrict__ outv, const float* __restrict__ pes,
    const float* __restrict__ Wpe, const float* __restrict__ bpe,
    unsigned short* __restrict__ tws)
{
    __shared__ float wpe_s[HD * PEC];
    __shared__ float bpe_s[HD];
    int tid = threadIdx.x;
    for (int idx = tid; idx < HD * PEC; idx += 256) wpe_s[idx] = Wpe[idx];
    if (tid < HD) bpe_s[tid] = bpe[tid];
    __syncthreads();

    int bh = blockIdx.y;
    int n  = blockIdx.x * 32 + (tid >> 3);
    int d0 = (tid & 7) * 8;
    int b = bh >> 3, h = bh & 7;

    float pr[PEC];
    const float* prow = pes + (bh * NSEQ + n) * PEC;
    #pragma unroll
    for (int c = 0; c < PEC; c += 4) {
        f32x4 t = *(const f32x4*)(prow + c);
        pr[c] = t[0]; pr[c + 1] = t[1]; pr[c + 2] = t[2]; pr[c + 3] = t[3];
    }
    const float* ovp = outv + (bh * NSEQ + n) * HD + d0;
    s16x8 pk;
    #pragma unroll
    for (int dd = 0; dd < 8; ++dd) {
        float acc = bpe_s[d0 + dd] + ovp[dd];
        const float* wrow = &wpe_s[(d0 + dd) * PEC];
        #pragma unroll
        for (int c = 0; c < PEC; ++c) acc += pr[c] * wrow[c];
        pk[dd] = (short)f2bf(acc);
    }
    *(s16x8*)(tws + (b * NSEQ + n) * INNER + h * HD + d0) = pk;
}

// ---------------------------------------------------------------------------
// K5: out[b][n][:] = t @ Wproj^T    (4096 x 128, K=512)
// ---------------------------------------------------------------------------
__global__ __launch_bounds__(256) void k_proj(
    const unsigned short* __restrict__ tws, const float* __restrict__ Wproj,
    float* __restrict__ out)
{
    int lane = threadIdx.x & 63, wave = threadIdx.x >> 6;
    int lr = lane & 15, lg = lane >> 4;
    int n0 = (blockIdx.x * 4 + wave) * 16;
    int m0 = blockIdx.y * 16;
    const unsigned short* arow = tws + (m0 + lr) * INNER;
    const float* brow = Wproj + (n0 + lr) * INNER;
    s16x8 afr[16];
    #pragma unroll
    for (int kt = 0; kt < 16; ++kt)
        afr[kt] = *(const s16x8*)(arow + kt * 32 + lg * 8);
    f32x4 acc = {0.f, 0.f, 0.f, 0.f};
    #pragma unroll
    for (int kt = 0; kt < 16; ++kt) {
        s16x8 bfr = load8bf(brow + kt * 32 + lg * 8);
        acc = mfma16(afr[kt], bfr, acc);
    }
    #pragma unroll
    for (int v = 0; v < 4; ++v)
        out[(m0 + lg * 4 + v) * DIM + n0 + lr] = acc[v];
}

// ---------------------------------------------------------------------------
// Workspace layout (92 MiB total):
//   [ 0,  4) MiB q_ws   bf16 [bh][n][64]
//   [ 4,  8) MiB k_ws   bf16 [bh][n][64]
//   [ 8, 12) MiB vT_ws  bf16 [bh][64][n]
//   [12, 76) MiB attn   bf16 [i][bh][j]
//   [76, 84) MiB outv   f32  [bh][n][64]
//   [84, 88) MiB pes    f32  [bh][n][32]
//   [88, 92) MiB t      bf16 [b][n][512]
// ---------------------------------------------------------------------------
extern "C" void kernel_launch(void* const* d_in, const int* in_sizes, int n_in,
                              void* d_out, int out_size, void* d_ws, size_t ws_size,
                              hipStream_t stream)
{
    const float* x     = (const float*)d_in[0];
    const float* pe    = (const float*)d_in[1];
    const float* Wq    = (const float*)d_in[2];
    const float* Wk    = (const float*)d_in[3];
    const float* Wv    = (const float*)d_in[4];
    const float* bv    = (const float*)d_in[5];
    const float* Wproj = (const float*)d_in[6];
    const float* Wpe   = (const float*)d_in[7];
    const float* bpe   = (const float*)d_in[8];
    float* out = (float*)d_out;

    char* ws = (char*)d_ws;
    unsigned short* qws  = (unsigned short*)(ws);
    unsigned short* kws  = (unsigned short*)(ws + ( 4u << 20));
    unsigned short* vtws = (unsigned short*)(ws + ( 8u << 20));
    unsigned short* attn = (unsigned short*)(ws + (12u << 20));
    float*          outv = (float*)         (ws + (76u << 20));
    float*          pes  = (float*)         (ws + (84u << 20));
    unsigned short* tws  = (unsigned short*)(ws + (88u << 20));

    k_qkv <<<dim3(24, 256), 256, 0, stream>>>(x, Wq, Wk, Wv, bv, qws, kws, vtws);
    k_attn<<<dim3(64, 32),  256, 0, stream>>>(qws, kws, vtws, attn, outv);
    k_pe  <<<dim3(1024),    256, 0, stream>>>(attn, pe, pes);
    k_comb<<<dim3(32, 32),  256, 0, stream>>>(outv, pes, Wpe, bpe, tws);
    k_proj<<<dim3(2, 256),  256, 0, stream>>>(tws, Wproj, out);
}

// Round 4
// 172.320 us; speedup vs baseline: 1.1181x; 1.1181x over previous
//
#include <hip/hip_runtime.h>
#include <hip/hip_bf16.h>

#define DIM   128
#define NH    8
#define INNER 512
#define HD    64
#define BSZ   4
#define NSEQ  1024
#define PEC   32
#define BH    32   // BSZ*NH

typedef __attribute__((ext_vector_type(4))) float f32x4;
typedef __attribute__((ext_vector_type(8))) short s16x8;
typedef __attribute__((ext_vector_type(4))) unsigned short u16x4;

__device__ __forceinline__ unsigned short f2bf(float f) {
    unsigned u = __float_as_uint(f);
    u += 0x7fffu + ((u >> 16) & 1u);
    return (unsigned short)(u >> 16);
}

__device__ __forceinline__ float bf2f(short s) {
    return __uint_as_float(((unsigned)(unsigned short)s) << 16);
}

__device__ __forceinline__ s16x8 load8bf(const float* p) {
    f32x4 a = *(const f32x4*)p;
    f32x4 b = *(const f32x4*)(p + 4);
    s16x8 r;
    r[0] = (short)f2bf(a[0]); r[1] = (short)f2bf(a[1]);
    r[2] = (short)f2bf(a[2]); r[3] = (short)f2bf(a[3]);
    r[4] = (short)f2bf(b[0]); r[5] = (short)f2bf(b[1]);
    r[6] = (short)f2bf(b[2]); r[7] = (short)f2bf(b[3]);
    return r;
}

__device__ __forceinline__ f32x4 mfma16(s16x8 a, s16x8 b, f32x4 c) {
    return __builtin_amdgcn_mfma_f32_16x16x32_bf16(a, b, c, 0, 0, 0);
}

// ---------------------------------------------------------------------------
// K1: q/k/v projections.  q_ws,k_ws: bf16 [bh][n][d]  (q pre-scaled by 1/8)
//     vT_ws: bf16 [bh][d][n]  (transposed, bias added)
// ---------------------------------------------------------------------------
__global__ __launch_bounds__(256) void k_qkv(
    const float* __restrict__ x,
    const float* __restrict__ Wq, const float* __restrict__ Wk,
    const float* __restrict__ Wv, const float* __restrict__ bv,
    unsigned short* __restrict__ qws, unsigned short* __restrict__ kws,
    unsigned short* __restrict__ vtws)
{
    int lane = threadIdx.x & 63, wave = threadIdx.x >> 6;
    int lr = lane & 15, lg = lane >> 4;
    int ct   = blockIdx.x * 4 + wave;   // 0..95 column tile over 1536 cols
    int col0 = ct * 16;
    int m0   = blockIdx.y * 16;

    s16x8 a[4];
    const float* xrow = x + (m0 + lr) * DIM;
    #pragma unroll
    for (int kt = 0; kt < 4; ++kt) a[kt] = load8bf(xrow + kt * 32 + lg * 8);

    const float* W; int cbase; int which = col0 >> 9;
    if (which == 0)      { W = Wq; cbase = col0; }
    else if (which == 1) { W = Wk; cbase = col0 - 512; }
    else                 { W = Wv; cbase = col0 - 1024; }

    const float* wrow = W + (cbase + lr) * DIM;
    s16x8 bfr[4];
    #pragma unroll
    for (int kt = 0; kt < 4; ++kt) bfr[kt] = load8bf(wrow + kt * 32 + lg * 8);
    f32x4 acc = {0.f, 0.f, 0.f, 0.f};
    #pragma unroll
    for (int kt = 0; kt < 4; ++kt) acc = mfma16(a[kt], bfr[kt], acc);

    int colW = cbase + lr;          // 0..511 inside this projection
    int h = colW >> 6, d = colW & 63;
    int mB = m0 + lg * 4;           // 4 consecutive rows, same batch
    int b  = mB >> 10;
    int bh = b * NH + h;
    if (which == 2) {
        float bias = bv[colW];
        u16x4 pk;
        #pragma unroll
        for (int v = 0; v < 4; ++v) pk[v] = f2bf(acc[v] + bias);
        int n0 = mB & 1023;
        *(u16x4*)(vtws + (bh * HD + d) * NSEQ + n0) = pk;
    } else {
        #pragma unroll
        for (int v = 0; v < 4; ++v) {
            int n = (mB + v) & 1023;
            float val = acc[v];
            if (which == 0) qws[(bh * NSEQ + n) * HD + d] = f2bf(val * 0.125f);
            else            kws[(bh * NSEQ + n) * HD + d] = f2bf(val);
        }
    }
}

// ---------------------------------------------------------------------------
// K2 v4: per (bh, 32 query rows): S = qk^T -> softmax -> attn bf16 [i][bh][j]
//     -> outv = P @ V (via vT) f32 [bh][n][d]
// QBLK=32 halves K/V re-read traffic; XCD-pinned mapping (bh = (L&7)*4+...)
// keeps each XCD's K/V working set (4 bh x 256 KB = 1 MB) L2-resident.
// grid 1024 linear, block 256 (4 waves).
// ---------------------------------------------------------------------------
__global__ __launch_bounds__(256) void k_attn(
    const unsigned short* __restrict__ qws, const unsigned short* __restrict__ kws,
    const unsigned short* __restrict__ vtws,
    unsigned short* __restrict__ attnw, float* __restrict__ outv)
{
    __shared__ unsigned short sS[32 * 1024];   // 64 KB bf16 [32][1024] swizzled
    int lane = threadIdx.x & 63, wave = threadIdx.x >> 6;
    int lr = lane & 15, lg = lane >> 4;

    int L = blockIdx.x;
    int bh = (L & 7) * 4 + ((L >> 3) & 3);   // XCD-pinned: 4 bh per XCD
    int i0 = (L >> 5) * 32;

    auto sp = [&](int r, int j) -> unsigned short* {
        unsigned byte = (unsigned)(r * 2048 + j * 2);
        byte ^= (unsigned)((r & 7) << 4);
        return (unsigned short*)((char*)sS + byte);
    };

    // ---- phase 1: scores; wave w covers j in [w*256, w*256+256), 2 row tiles
    s16x8 qf[2][2];
    #pragma unroll
    for (int m = 0; m < 2; ++m) {
        const unsigned short* qrow = qws + (bh * NSEQ + i0 + m * 16 + lr) * HD;
        qf[m][0] = *(const s16x8*)(qrow + lg * 8);
        qf[m][1] = *(const s16x8*)(qrow + 32 + lg * 8);
    }
    #pragma unroll
    for (int jt = 0; jt < 16; ++jt) {
        int j0 = wave * 256 + jt * 16;
        const unsigned short* krow = kws + (bh * NSEQ + j0 + lr) * HD + lg * 8;
        s16x8 kf0 = *(const s16x8*)(krow);
        s16x8 kf1 = *(const s16x8*)(krow + 32);
        #pragma unroll
        for (int m = 0; m < 2; ++m) {
            f32x4 acc = {0.f, 0.f, 0.f, 0.f};
            acc = mfma16(qf[m][0], kf0, acc);
            acc = mfma16(qf[m][1], kf1, acc);
            #pragma unroll
            for (int v = 0; v < 4; ++v)
                *sp(m * 16 + lg * 4 + v, j0 + lr) = f2bf(acc[v]);
        }
    }
    __syncthreads();

    // ---- phase 2: softmax, 8 threads/row over 32 rows ----
    int r = threadIdx.x >> 3, c = threadIdx.x & 7;
    float mx = -3.0e38f;
    #pragma unroll
    for (int it = 0; it < 16; ++it) {
        s16x8 sv = *(s16x8*)sp(r, it * 64 + c * 8);
        #pragma unroll
        for (int u = 0; u < 8; ++u) mx = fmaxf(mx, bf2f(sv[u]));
    }
    #pragma unroll
    for (int off = 4; off; off >>= 1) mx = fmaxf(mx, __shfl_xor(mx, off, 8));

    float sum = 0.f;
    #pragma unroll
    for (int it = 0; it < 16; ++it) {
        unsigned short* p = sp(r, it * 64 + c * 8);
        s16x8 sv = *(s16x8*)p;
        s16x8 ev;
        #pragma unroll
        for (int u = 0; u < 8; ++u) {
            float e = __expf(bf2f(sv[u]) - mx);
            sum += e;
            ev[u] = (short)f2bf(e);
        }
        *(s16x8*)p = ev;
    }
    #pragma unroll
    for (int off = 4; off; off >>= 1) sum += __shfl_xor(sum, off, 8);
    float inv = 1.0f / sum;

    unsigned short* arow = attnw + ((size_t)(i0 + r) * BH + bh) * NSEQ;
    #pragma unroll
    for (int it = 0; it < 16; ++it) {
        unsigned short* p = sp(r, it * 64 + c * 8);
        s16x8 ev = *(s16x8*)p;
        s16x8 pv;
        #pragma unroll
        for (int u = 0; u < 8; ++u) pv[u] = (short)f2bf(bf2f(ev[u]) * inv);
        *(s16x8*)p = pv;
        *(s16x8*)(arow + it * 64 + c * 8) = pv;
    }
    __syncthreads();

    // ---- phase 3: outv = P @ V ; wave w owns d quarter, 2 row tiles ----
    int d0 = wave * 16;
    const unsigned short* vrow = vtws + (bh * HD + d0 + lr) * NSEQ + lg * 8;
    f32x4 oacc0 = {0.f, 0.f, 0.f, 0.f};
    f32x4 oacc1 = {0.f, 0.f, 0.f, 0.f};
    #pragma unroll
    for (int kt = 0; kt < 32; ++kt) {
        s16x8 vf = *(const s16x8*)(vrow + kt * 32);
        s16x8 af0 = *(const s16x8*)sp(lr,      kt * 32 + lg * 8);
        s16x8 af1 = *(const s16x8*)sp(16 + lr, kt * 32 + lg * 8);
        oacc0 = mfma16(af0, vf, oacc0);
        oacc1 = mfma16(af1, vf, oacc1);
    }
    float* orow = outv + (bh * NSEQ + i0) * HD;
    #pragma unroll
    for (int v = 0; v < 4; ++v) {
        orow[(lg * 4 + v) * HD + d0 + lr]        = oacc0[v];
        orow[(16 + lg * 4 + v) * HD + d0 + lr]   = oacc1[v];
    }
}

// ---------------------------------------------------------------------------
// K3: per query row i: pes[bh][i][c] = attn[i] (32bh x 1024j) @ pe[i] (1024j x 32c)
// grid (1024), block 256: 4 waves = 2 bh-halves x 2 c-halves.
// ---------------------------------------------------------------------------
__global__ __launch_bounds__(256) void k_pe(
    const unsigned short* __restrict__ attnw, const float* __restrict__ pe,
    float* __restrict__ pes)
{
    __shared__ unsigned short pt[2][PEC][136];   // 17.4 KB
    int i = blockIdx.x;
    int tid = threadIdx.x;
    int lane = tid & 63, wave = tid >> 6;
    int lr = lane & 15, lg = lane >> 4;
    int bh0 = (wave >> 1) * 16;
    int c0  = (wave & 1) * 16;
    const float* pei = pe + (size_t)i * NSEQ * PEC;
    int jp = tid & 63;        // j-pair index (covers 2 consecutive j)
    int cg = tid >> 6;        // c-octet

    // preload ALL attn A-fragments (64 VGPRs, consumed across the loop)
    s16x8 af[32];
    {
        const unsigned short* arow = attnw + ((size_t)i * BH + bh0 + lr) * NSEQ + lg * 8;
        #pragma unroll
        for (int t = 0; t < 32; ++t) af[t] = *(const s16x8*)(arow + t * 32);
    }

    f32x4 r0, r1, r2, r3;     // pe stage registers
    auto issue = [&](int blk) {
        const float* s0 = pei + (size_t)(blk * 128 + jp * 2) * PEC + cg * 8;
        r0 = *(const f32x4*)(s0);
        r1 = *(const f32x4*)(s0 + 4);
        r2 = *(const f32x4*)(s0 + PEC);
        r3 = *(const f32x4*)(s0 + PEC + 4);
    };
    auto commit = [&](int buf) {
        #pragma unroll
        for (int cc = 0; cc < 4; ++cc) {
            unsigned lo = f2bf(r0[cc]), hi = f2bf(r2[cc]);
            *(unsigned*)&pt[buf][cg * 8 + cc][jp * 2] = lo | (hi << 16);
        }
        #pragma unroll
        for (int cc = 0; cc < 4; ++cc) {
            unsigned lo = f2bf(r1[cc]), hi = f2bf(r3[cc]);
            *(unsigned*)&pt[buf][cg * 8 + 4 + cc][jp * 2] = lo | (hi << 16);
        }
    };

    issue(0); commit(0);
    __syncthreads();

    f32x4 acc = {0.f, 0.f, 0.f, 0.f};
    #pragma unroll
    for (int blk = 0; blk < 8; ++blk) {
        int cur = blk & 1;
        if (blk < 7) issue(blk + 1);
        #pragma unroll
        for (int kt = 0; kt < 4; ++kt) {
            s16x8 bf = *(const s16x8*)&pt[cur][c0 + lr][kt * 32 + lg * 8];
            acc = mfma16(af[blk * 4 + kt], bf, acc);
        }
        if (blk < 7) commit(cur ^ 1);
        __syncthreads();
    }
    #pragma unroll
    for (int v = 0; v < 4; ++v)
        pes[((bh0 + lg * 4 + v) * NSEQ + i) * PEC + c0 + lr] = acc[v];
}

// ---------------------------------------------------------------------------
// K4: t[b][n][h*64+d] = outv + pes @ Wpe^T + bpe   (bf16 packed)
// ---------------------------------------------------------------------------
__global__ __launch_bounds__(256) void k_comb(
    const float* __restrict__ outv, const float* __restrict__ pes,
    const float* __restrict__ Wpe, const float* __restrict__ bpe,
    unsigned short* __restrict__ tws)
{
    __shared__ float wpe_s[HD * PEC];
    __shared__ float bpe_s[HD];
    int tid = threadIdx.x;
    for (int idx = tid; idx < HD * PEC; idx += 256) wpe_s[idx] = Wpe[idx];
    if (tid < HD) bpe_s[tid] = bpe[tid];
    __syncthreads();

    int bh = blockIdx.y;
    int n  = blockIdx.x * 32 + (tid >> 3);
    int d0 = (tid & 7) * 8;
    int b = bh >> 3, h = bh & 7;

    float pr[PEC];
    const float* prow = pes + (bh * NSEQ + n) * PEC;
    #pragma unroll
    for (int c = 0; c < PEC; c += 4) {
        f32x4 t = *(const f32x4*)(prow + c);
        pr[c] = t[0]; pr[c + 1] = t[1]; pr[c + 2] = t[2]; pr[c + 3] = t[3];
    }
    const float* ovp = outv + (bh * NSEQ + n) * HD + d0;
    s16x8 pk;
    #pragma unroll
    for (int dd = 0; dd < 8; ++dd) {
        float acc = bpe_s[d0 + dd] + ovp[dd];
        const float* wrow = &wpe_s[(d0 + dd) * PEC];
        #pragma unroll
        for (int c = 0; c < PEC; ++c) acc += pr[c] * wrow[c];
        pk[dd] = (short)f2bf(acc);
    }
    *(s16x8*)(tws + (b * NSEQ + n) * INNER + h * HD + d0) = pk;
}

// ---------------------------------------------------------------------------
// K5: out[b][n][:] = t @ Wproj^T    (4096 x 128, K=512)
// ---------------------------------------------------------------------------
__global__ __launch_bounds__(256) void k_proj(
    const unsigned short* __restrict__ tws, const float* __restrict__ Wproj,
    float* __restrict__ out)
{
    int lane = threadIdx.x & 63, wave = threadIdx.x >> 6;
    int lr = lane & 15, lg = lane >> 4;
    int n0 = (blockIdx.x * 4 + wave) * 16;
    int m0 = blockIdx.y * 16;
    const unsigned short* arow = tws + (m0 + lr) * INNER;
    const float* brow = Wproj + (n0 + lr) * INNER;
    s16x8 afr[16];
    #pragma unroll
    for (int kt = 0; kt < 16; ++kt)
        afr[kt] = *(const s16x8*)(arow + kt * 32 + lg * 8);
    f32x4 acc = {0.f, 0.f, 0.f, 0.f};
    #pragma unroll
    for (int kt = 0; kt < 16; ++kt) {
        s16x8 bfr = load8bf(brow + kt * 32 + lg * 8);
        acc = mfma16(afr[kt], bfr, acc);
    }
    #pragma unroll
    for (int v = 0; v < 4; ++v)
        out[(m0 + lg * 4 + v) * DIM + n0 + lr] = acc[v];
}

// ---------------------------------------------------------------------------
// Workspace layout (92 MiB total):
//   [ 0,  4) MiB q_ws   bf16 [bh][n][64]
//   [ 4,  8) MiB k_ws   bf16 [bh][n][64]
//   [ 8, 12) MiB vT_ws  bf16 [bh][64][n]
//   [12, 76) MiB attn   bf16 [i][bh][j]
//   [76, 84) MiB outv   f32  [bh][n][64]
//   [84, 88) MiB pes    f32  [bh][n][32]
//   [88, 92) MiB t      bf16 [b][n][512]
// ---------------------------------------------------------------------------
extern "C" void kernel_launch(void* const* d_in, const int* in_sizes, int n_in,
                              void* d_out, int out_size, void* d_ws, size_t ws_size,
                              hipStream_t stream)
{
    const float* x     = (const float*)d_in[0];
    const float* pe    = (const float*)d_in[1];
    const float* Wq    = (const float*)d_in[2];
    const float* Wk    = (const float*)d_in[3];
    const float* Wv    = (const float*)d_in[4];
    const float* bv    = (const float*)d_in[5];
    const float* Wproj = (const float*)d_in[6];
    const float* Wpe   = (const float*)d_in[7];
    const float* bpe   = (const float*)d_in[8];
    float* out = (float*)d_out;

    char* ws = (char*)d_ws;
    unsigned short* qws  = (unsigned short*)(ws);
    unsigned short* kws  = (unsigned short*)(ws + ( 4u << 20));
    unsigned short* vtws = (unsigned short*)(ws + ( 8u << 20));
    unsigned short* attn = (unsigned short*)(ws + (12u << 20));
    float*          outv = (float*)         (ws + (76u << 20));
    float*          pes  = (float*)         (ws + (84u << 20));
    unsigned short* tws  = (unsigned short*)(ws + (88u << 20));

    k_qkv <<<dim3(24, 256), 256, 0, stream>>>(x, Wq, Wk, Wv, bv, qws, kws, vtws);
    k_attn<<<dim3(1024),    256, 0, stream>>>(qws, kws, vtws, attn, outv);
    k_pe  <<<dim3(1024),    256, 0, stream>>>(attn, pe, pes);
    k_comb<<<dim3(32, 32),  256, 0, stream>>>(outv, pes, Wpe, bpe, tws);
    k_proj<<<dim3(2, 256),  256, 0, stream>>>(tws, Wproj, out);
}